// Round 1
// baseline (965.878 us; speedup 1.0000x reference)
//
#include <hip/hip_runtime.h>
#include <hip/hip_bf16.h>
#include <math.h>

namespace {
constexpr int CDIM   = 128;
constexpr int KCODES = 1024;
constexpr int HWSZ   = 4096;   // 64*64
constexpr int BATCH  = 16;
constexpr int NPOS   = BATCH * HWSZ;            // 65536
constexpr int TK     = 64;                      // codes per LDS tile
constexpr int NTILES = KCODES / TK;             // 16
constexpr size_t QELEMS   = (size_t)BATCH * CDIM * HWSZ;   // 8388608
constexpr size_t IDX_OFF  = QELEMS;                        // float32 elements
constexpr size_t LOSS_OFF = IDX_OFF + (size_t)NPOS;        // 8454144
constexpr size_t PERP_OFF = LOSS_OFF + 1;
// d_ws float-element offsets
constexpr int WS_C2   = 0;      // [0,1024)   float ||c_k||^2 (numpy-bit-exact)
constexpr int WS_HIST = 1024;   // [1024,2048) uint  usage counts
constexpr int WS_LOSS = 2048;   // [2048]     float sum ||z-q||^2
constexpr float INV_TOTAL = 1.0f / (float)QELEMS;
constexpr float INV_NPOS  = 1.0f / (float)NPOS;
}

// Bit-exact replica of numpy pairwise_sum for n=128 contiguous float32 applied
// to elementwise squares: 8 accumulator chains (stride 8), sequential within a
// chain, combined ((r0+r1)+(r2+r3))+((r4+r5)+(r6+r7)). __f*_rn forbids fma
// contraction (numpy multiplies into a temp, then adds — never fused).
__device__ __forceinline__ float np_sumsq_128(const float* v) {
    float r[8];
    #pragma unroll
    for (int j = 0; j < 8; ++j) r[j] = __fmul_rn(v[j], v[j]);
    #pragma unroll
    for (int i = 8; i < 128; i += 8) {
        #pragma unroll
        for (int j = 0; j < 8; ++j)
            r[j] = __fadd_rn(r[j], __fmul_rn(v[i + j], v[i + j]));
    }
    const float s01 = __fadd_rn(r[0], r[1]);
    const float s23 = __fadd_rn(r[2], r[3]);
    const float s45 = __fadd_rn(r[4], r[5]);
    const float s67 = __fadd_rn(r[6], r[7]);
    return __fadd_rn(__fadd_rn(s01, s23), __fadd_rn(s45, s67));
}

// ---- pass 0: codebook norms (numpy-bit-exact) + zero accumulators ----------
__global__ __launch_bounds__(256) void vq_prep(const float* __restrict__ cb,
                                               float* __restrict__ ws) {
    const int k = blockIdx.x * 256 + threadIdx.x;   // 0..1023
    const float* row = cb + (size_t)k * CDIM;
    float rr[CDIM];
    #pragma unroll
    for (int c = 0; c < CDIM; ++c) rr[c] = row[c];
    ws[WS_C2 + k] = np_sumsq_128(rr);
    ((unsigned int*)ws)[WS_HIST + k] = 0u;
    if (k == 0) ws[WS_LOSS] = 0.0f;
}

// ---- pass 1: argmin with numpy-replicated rounding chain -------------------
// launch_bounds(256,1): grid is 256 blocks == 1 block/CU, so the allocator has
// the full 512-VGPR budget. That alone was NOT enough: with remat allowed the
// compiler still chose VGPR=88 and reloaded zr from global inside the k-loop
// (measured: VGPR_Count=88, VALUBusy 26%, 927 us — the documented Round-4
// failure mode). Fix: pin every zr[c] with an empty asm volatile. Asm-defined
// values cannot be rematerialized, so all 128 stay resident in VGPRs. Values
// are unchanged -> numpy bit-exactness of z2 and the fma chains is preserved.
__global__ __launch_bounds__(256, 1) void vq_main(const float* __restrict__ z,
                                                  const float* __restrict__ cb,
                                                  float* __restrict__ ws,
                                                  float* __restrict__ out) {
    __shared__ __align__(16) float tile[TK * CDIM];   // 32 KB
    __shared__ unsigned int lhist[KCODES];            // 4 KB
    __shared__ float red[256];

    const int tid = threadIdx.x;
    const int n   = blockIdx.x * 256 + tid;
    const int b   = n >> 12;
    const int hw  = n & (HWSZ - 1);
    const float* zp  = z + (size_t)b * CDIM * HWSZ + hw;
    const float* c2g = ws + WS_C2;

    for (int i = tid; i < KCODES; i += 256) lhist[i] = 0u;

    float zr[CDIM];
    #pragma unroll
    for (int c = 0; c < CDIM; ++c) zr[c] = zp[(size_t)c * HWSZ];
    // Pin: force each element into a VGPR and make it non-rematerializable.
    // Without this the allocator reloads z (16KB-strided, L1-hostile) inside
    // the inner loop and the kernel is latency-bound at 26% VALU.
    #pragma unroll
    for (int c = 0; c < CDIM; ++c) asm volatile("" : "+v"(zr[c]));

    // z2 bit-identical to np.sum(z_flat*z_flat, axis=1)
    const float z2 = np_sumsq_128(zr);

    float best_d = INFINITY;
    int   best_k = 0;

    for (int t = 0; t < NTILES; ++t) {
        __syncthreads();
        const float4* src = (const float4*)(cb + (size_t)t * TK * CDIM);
        float4* dst = (float4*)tile;
        #pragma unroll
        for (int i = 0; i < (TK * CDIM / 4) / 256; ++i)
            dst[i * 256 + tid] = src[i * 256 + tid];
        __syncthreads();

        const int kbase = t * TK;
        for (int kk = 0; kk < TK; kk += 4) {
            const float4* p0 = (const float4*)(tile + (kk + 0) * CDIM);
            const float4* p1 = (const float4*)(tile + (kk + 1) * CDIM);
            const float4* p2 = (const float4*)(tile + (kk + 2) * CDIM);
            const float4* p3 = (const float4*)(tile + (kk + 3) * CDIM);
            // one sequential ascending-c fma chain per code (BLAS-like order)
            float a0 = 0.f, a1 = 0.f, a2 = 0.f, a3 = 0.f;
            #pragma unroll
            for (int q = 0; q < CDIM / 4; ++q) {
                const float4 v0 = p0[q], v1 = p1[q], v2 = p2[q], v3 = p3[q];
                const float zx = zr[4*q+0], zy = zr[4*q+1];
                const float zz = zr[4*q+2], zw = zr[4*q+3];
                a0 = fmaf(v0.x, zx, a0); a0 = fmaf(v0.y, zy, a0);
                a0 = fmaf(v0.z, zz, a0); a0 = fmaf(v0.w, zw, a0);
                a1 = fmaf(v1.x, zx, a1); a1 = fmaf(v1.y, zy, a1);
                a1 = fmaf(v1.z, zz, a1); a1 = fmaf(v1.w, zw, a1);
                a2 = fmaf(v2.x, zx, a2); a2 = fmaf(v2.y, zy, a2);
                a2 = fmaf(v2.z, zz, a2); a2 = fmaf(v2.w, zw, a2);
                a3 = fmaf(v3.x, zx, a3); a3 = fmaf(v3.y, zy, a3);
                a3 = fmaf(v3.z, zz, a3); a3 = fmaf(v3.w, zw, a3);
            }
            // d = fl(fl(z2 - 2*zc) + c2): fmaf(-2,a,z2) == fl(z2-2a) since 2a
            // exact; __fadd_rn forbids contraction of the final add.
            const float d0 = __fadd_rn(fmaf(-2.0f, a0, z2), c2g[kbase + kk + 0]);
            const float d1 = __fadd_rn(fmaf(-2.0f, a1, z2), c2g[kbase + kk + 1]);
            const float d2 = __fadd_rn(fmaf(-2.0f, a2, z2), c2g[kbase + kk + 2]);
            const float d3 = __fadd_rn(fmaf(-2.0f, a3, z2), c2g[kbase + kk + 3]);
            // strict < ascending k == np.argmin first-index tie-break
            if (d0 < best_d) { best_d = d0; best_k = kbase + kk + 0; }
            if (d1 < best_d) { best_d = d1; best_k = kbase + kk + 1; }
            if (d2 < best_d) { best_d = d2; best_k = kbase + kk + 2; }
            if (d3 < best_d) { best_d = d3; best_k = kbase + kk + 3; }
        }
    }

    // quantized output: fp32 gather of winning codebook row
    const float4* q4 = (const float4*)(cb + (size_t)best_k * CDIM);
    float* op = out + (size_t)b * CDIM * HWSZ + hw;
    #pragma unroll
    for (int q = 0; q < CDIM / 4; ++q) {
        const float4 v = q4[q];
        op[(size_t)(4 * q + 0) * HWSZ] = v.x;
        op[(size_t)(4 * q + 1) * HWSZ] = v.y;
        op[(size_t)(4 * q + 2) * HWSZ] = v.z;
        op[(size_t)(4 * q + 3) * HWSZ] = v.w;
    }

    // index output (fp32)
    out[IDX_OFF + (size_t)n] = (float)best_k;

    // loss: best_d == fl(||z-q||^2), ~128 magnitude, 2% slack
    atomicAdd(&lhist[best_k], 1u);
    red[tid] = best_d;
    __syncthreads();
    for (int s = 128; s > 0; s >>= 1) {
        if (tid < s) red[tid] += red[tid + s];
        __syncthreads();
    }
    if (tid == 0) atomicAdd(&ws[WS_LOSS], red[0]);

    unsigned int* ghist = (unsigned int*)ws + WS_HIST;
    for (int i = tid; i < KCODES; i += 256) {
        const unsigned int v = lhist[i];
        if (v) atomicAdd(&ghist[i], v);
    }
}

// ---- pass 2: scalars --------------------------------------------------------
__global__ __launch_bounds__(1024) void vq_final(const float* __restrict__ ws,
                                                 float* __restrict__ out) {
    __shared__ float red[1024];
    const int t = threadIdx.x;
    const unsigned int* hist = (const unsigned int*)ws + WS_HIST;
    const float p = (float)hist[t] * INV_NPOS;
    red[t] = p * logf(p + 1e-10f);
    __syncthreads();
    for (int s = 512; s > 0; s >>= 1) {
        if (t < s) red[t] += red[t + s];
        __syncthreads();
    }
    if (t == 0) {
        out[LOSS_OFF] = 1.25f * (ws[WS_LOSS] * INV_TOTAL);   // cb + 0.25*commit
        out[PERP_OFF] = expf(-red[0]);
    }
}

extern "C" void kernel_launch(void* const* d_in, const int* in_sizes, int n_in,
                              void* d_out, int out_size, void* d_ws, size_t ws_size,
                              hipStream_t stream) {
    const float* z  = (const float*)d_in[0];
    const float* cb = (const float*)d_in[1];
    float* out = (float*)d_out;
    float* ws  = (float*)d_ws;

    vq_prep <<<KCODES / 256, 256, 0, stream>>>(cb, ws);
    vq_main <<<NPOS / 256,   256, 0, stream>>>(z, cb, ws, out);
    vq_final<<<1,           1024, 0, stream>>>(ws, out);
}

// Round 2
// 364.473 us; speedup vs baseline: 2.6501x; 2.6501x over previous
//
#include <hip/hip_runtime.h>
#include <math.h>

namespace {
constexpr int CDIM   = 128;
constexpr int KCODES = 1024;
constexpr int HWSZ   = 4096;   // 64*64
constexpr int BATCH  = 16;
constexpr int NPOS   = BATCH * HWSZ;            // 65536
constexpr int P      = 128;                     // positions per block
constexpr int TK     = 64;                      // codes per LDS tile
constexpr int NTILES = KCODES / TK;             // 16
constexpr size_t QELEMS   = (size_t)BATCH * CDIM * HWSZ;   // 8388608
constexpr size_t IDX_OFF  = QELEMS;                        // float32 elements
constexpr size_t LOSS_OFF = IDX_OFF + (size_t)NPOS;        // 8454144
constexpr size_t PERP_OFF = LOSS_OFF + 1;
// d_ws float-element offsets
constexpr int WS_C2   = 0;      // [0,1024)   float ||c_k||^2 (numpy-bit-exact)
constexpr int WS_HIST = 1024;   // [1024,2048) uint  usage counts
constexpr int WS_LOSS = 2048;   // [2048]     float sum ||z-q||^2
constexpr float INV_TOTAL = 1.0f / (float)QELEMS;
constexpr float INV_NPOS  = 1.0f / (float)NPOS;
}

// Bit-exact replica of numpy pairwise_sum for n=128 contiguous float32 applied
// to elementwise squares: 8 accumulator chains (stride 8), sequential within a
// chain, combined ((r0+r1)+(r2+r3))+((r4+r5)+(r6+r7)). __f*_rn forbids fma
// contraction (numpy multiplies into a temp, then adds — never fused).
__device__ __forceinline__ float np_sumsq_128(const float* v) {
    float r[8];
    #pragma unroll
    for (int j = 0; j < 8; ++j) r[j] = __fmul_rn(v[j], v[j]);
    #pragma unroll
    for (int i = 8; i < 128; i += 8) {
        #pragma unroll
        for (int j = 0; j < 8; ++j)
            r[j] = __fadd_rn(r[j], __fmul_rn(v[i + j], v[i + j]));
    }
    const float s01 = __fadd_rn(r[0], r[1]);
    const float s23 = __fadd_rn(r[2], r[3]);
    const float s45 = __fadd_rn(r[4], r[5]);
    const float s67 = __fadd_rn(r[6], r[7]);
    return __fadd_rn(__fadd_rn(s01, s23), __fadd_rn(s45, s67));
}

// ---- pass 0: codebook norms (numpy-bit-exact) + zero accumulators ----------
__global__ __launch_bounds__(256) void vq_prep(const float* __restrict__ cb,
                                               float* __restrict__ ws) {
    const int k = blockIdx.x * 256 + threadIdx.x;   // 0..1023
    const float* row = cb + (size_t)k * CDIM;
    float rr[CDIM];
    #pragma unroll
    for (int c = 0; c < CDIM; ++c) rr[c] = row[c];
    ws[WS_C2 + k] = np_sumsq_128(rr);
    ((unsigned int*)ws)[WS_HIST + k] = 0u;
    if (k == 0) ws[WS_LOSS] = 0.0f;
}

// ---- pass 1: register-blocked GEMM-style argmin -----------------------------
// Restructure (Round 1): the per-thread zr[128] live-across-the-k-loop array
// is un-allocatable (two sessions measured VGPR=88 + scratch/global reloads +
// VALUBusy 26%). Instead: classic register tiling. Block = 128 positions x all
// 1024 codes; thread tile = 4 pos x 8 codes = 32 accumulators; both operands
// stream through LDS per channel c. Live set ~75 VGPRs -> nothing to spill.
// Bit-exactness: per (pos,code) the dot is ONE ascending-c fma chain (same as
// before == BLAS-like reference order); z2 is the numpy pairwise 8-chain; d
// formula and strict-< ascending-k argmin unchanged. Cross-thread combine is
// lexicographic (d,k) min over disjoint code subsets == np.argmin first-index.
__global__ __launch_bounds__(256, 1) void vq_main(const float* __restrict__ z,
                                                  const float* __restrict__ cb,
                                                  float* __restrict__ ws,
                                                  float* __restrict__ out) {
    __shared__ __align__(16) float zt[CDIM][P];     // 64 KB  zt[c][p]
    __shared__ __align__(16) float tile[TK][CDIM];  // 32 KB  tile[k][c]
    __shared__ float z2s[P];                        // 512 B
    __shared__ float bdls[8][P];                    // 4 KB  per-cg best_d
    __shared__ int   bkls[8][P];                    // 4 KB  per-cg best_k
    __shared__ int   wkls[P];                       // 512 B winning code
    __shared__ float red[256];                      // 1 KB
    __shared__ unsigned int lhist[KCODES];          // 4 KB   (total ~112.5 KB)

    const int tid   = threadIdx.x;
    const int nbase = blockIdx.x * P;
    const int b     = nbase >> 12;          // 4096 positions per batch image
    const int hw0   = nbase & (HWSZ - 1);   // 128-aligned
    const float* zb = z + (size_t)b * CDIM * HWSZ + hw0;

    for (int i = tid; i < KCODES; i += 256) lhist[i] = 0u;

    // ---- stage z strip: zt[c][p] = z[b][c][hw0+p] (coalesced, conflict-free)
    #pragma unroll
    for (int i = 0; i < (CDIM * P / 4) / 256; ++i) {   // 16 iters
        const int linear = i * 256 + tid;              // 0..4095
        const int c  = linear >> 5;
        const int p4 = (linear & 31) * 4;
        *(float4*)&zt[c][p4] = *(const float4*)(zb + (size_t)c * HWSZ + p4);
    }
    __syncthreads();

    // ---- z2 per position: numpy pairwise 8-chain, streamed from LDS --------
    if (tid < P) {
        const int p = tid;
        float r[8];
        #pragma unroll
        for (int j = 0; j < 8; ++j) {
            const float x = zt[j][p];
            r[j] = __fmul_rn(x, x);
        }
        #pragma unroll
        for (int i = 8; i < CDIM; i += 8) {
            #pragma unroll
            for (int j = 0; j < 8; ++j) {
                const float x = zt[i + j][p];
                r[j] = __fadd_rn(r[j], __fmul_rn(x, x));
            }
        }
        const float s01 = __fadd_rn(r[0], r[1]);
        const float s23 = __fadd_rn(r[2], r[3]);
        const float s45 = __fadd_rn(r[4], r[5]);
        const float s67 = __fadd_rn(r[6], r[7]);
        z2s[p] = __fadd_rn(__fadd_rn(s01, s23), __fadd_rn(s45, s67));
    }
    __syncthreads();

    const int pg = tid & 31;     // position group: positions p0..p0+3
    const int cg = tid >> 5;     // code group: codes k0..k0+7 within each tile
    const int p0 = pg * 4;
    const int k0 = cg * 8;
    const float* c2g = ws + WS_C2;

    float z2r[4];
    #pragma unroll
    for (int i = 0; i < 4; ++i) z2r[i] = z2s[p0 + i];

    float bestd[4] = {INFINITY, INFINITY, INFINITY, INFINITY};
    int   bestk[4] = {0, 0, 0, 0};

    for (int t = 0; t < NTILES; ++t) {
        __syncthreads();
        {   // stage code tile [k][c]: straight contiguous copy
            const float4* src = (const float4*)(cb + (size_t)t * TK * CDIM);
            float4* dst = (float4*)tile;
            #pragma unroll
            for (int i = 0; i < (TK * CDIM / 4) / 256; ++i)
                dst[i * 256 + tid] = src[i * 256 + tid];
        }
        __syncthreads();

        float a[4][8];
        #pragma unroll
        for (int i = 0; i < 4; ++i)
            #pragma unroll
            for (int j = 0; j < 8; ++j) a[i][j] = 0.0f;

        // 32 independent fma chains, each ascending c (reference order).
        // z-frag: 1 ds_read_b128, conflict-free (lanes 0-31 contiguous 512B,
        // lanes 32-63 broadcast). code reads: 2 distinct addrs/wave = free.
        #pragma unroll 8
        for (int c = 0; c < CDIM; ++c) {
            const float4 zv = *(const float4*)&zt[c][p0];
            float cv[8];
            #pragma unroll
            for (int j = 0; j < 8; ++j) cv[j] = tile[k0 + j][c];
            #pragma unroll
            for (int j = 0; j < 8; ++j) {
                a[0][j] = fmaf(zv.x, cv[j], a[0][j]);
                a[1][j] = fmaf(zv.y, cv[j], a[1][j]);
                a[2][j] = fmaf(zv.z, cv[j], a[2][j]);
                a[3][j] = fmaf(zv.w, cv[j], a[3][j]);
            }
        }

        // d = fl(fl(z2 - 2*zc) + c2); strict < with ascending k (t, then j)
        const int kb = t * TK + k0;
        #pragma unroll
        for (int j = 0; j < 8; ++j) {
            const float c2 = c2g[kb + j];
            #pragma unroll
            for (int i = 0; i < 4; ++i) {
                const float d = __fadd_rn(fmaf(-2.0f, a[i][j], z2r[i]), c2);
                if (d < bestd[i]) { bestd[i] = d; bestk[i] = kb + j; }
            }
        }
    }

    #pragma unroll
    for (int i = 0; i < 4; ++i) {
        bdls[cg][p0 + i] = bestd[i];
        bkls[cg][p0 + i] = bestk[i];
    }
    __syncthreads();

    // ---- combine 8 disjoint code-subsets per position; lexicographic (d,k)
    if (tid < P) {
        const int p = tid;
        float bd = bdls[0][p];
        int   bk = bkls[0][p];
        #pragma unroll
        for (int g = 1; g < 8; ++g) {
            const float d = bdls[g][p];
            const int   k = bkls[g][p];
            if (d < bd || (d == bd && k < bk)) { bd = d; bk = k; }
        }
        wkls[p] = bk;
        out[IDX_OFF + (size_t)(nbase + p)] = (float)bk;
        atomicAdd(&lhist[bk], 1u);
        red[tid] = bd;     // best_d == fl(||z-q||^2), loss has 2% slack
    } else {
        red[tid] = 0.0f;
    }
    __syncthreads();
    for (int s = 128; s > 0; s >>= 1) {
        if (tid < s) red[tid] += red[tid + s];
        __syncthreads();
    }
    if (tid == 0) atomicAdd(&ws[WS_LOSS], red[0]);

    // ---- quantized output: out[b][c][hw0+p] = cb[wk[p]][c] -----------------
    // lanes share c, contiguous p -> contiguous 256B stores; cb gather is
    // L1/L2-hot (512KB codebook).
    float* ob = out + (size_t)b * CDIM * HWSZ + hw0;
    #pragma unroll
    for (int i = 0; i < (CDIM * P) / 256; ++i) {   // 64 iters
        const int linear = i * 256 + tid;          // 0..16383
        const int c = linear >> 7;
        const int p = linear & 127;
        ob[(size_t)c * HWSZ + p] = cb[(size_t)wkls[p] * CDIM + c];
    }

    unsigned int* ghist = (unsigned int*)ws + WS_HIST;
    for (int i = tid; i < KCODES; i += 256) {
        const unsigned int v = lhist[i];
        if (v) atomicAdd(&ghist[i], v);
    }
}

// ---- pass 2: scalars --------------------------------------------------------
__global__ __launch_bounds__(1024) void vq_final(const float* __restrict__ ws,
                                                 float* __restrict__ out) {
    __shared__ float red[1024];
    const int t = threadIdx.x;
    const unsigned int* hist = (const unsigned int*)ws + WS_HIST;
    const float p = (float)hist[t] * INV_NPOS;
    red[t] = p * logf(p + 1e-10f);
    __syncthreads();
    for (int s = 512; s > 0; s >>= 1) {
        if (t < s) red[t] += red[t + s];
        __syncthreads();
    }
    if (t == 0) {
        out[LOSS_OFF] = 1.25f * (ws[WS_LOSS] * INV_TOTAL);   // cb + 0.25*commit
        out[PERP_OFF] = expf(-red[0]);
    }
}

extern "C" void kernel_launch(void* const* d_in, const int* in_sizes, int n_in,
                              void* d_out, int out_size, void* d_ws, size_t ws_size,
                              hipStream_t stream) {
    const float* z  = (const float*)d_in[0];
    const float* cb = (const float*)d_in[1];
    float* out = (float*)d_out;
    float* ws  = (float*)d_ws;

    vq_prep <<<KCODES / 256, 256, 0, stream>>>(cb, ws);
    vq_main <<<NPOS / P,     256, 0, stream>>>(z, cb, ws, out);
    vq_final<<<1,           1024, 0, stream>>>(ws, out);
}

// Round 3
// 355.705 us; speedup vs baseline: 2.7154x; 1.0246x over previous
//
#include <hip/hip_runtime.h>
#include <math.h>

namespace {
constexpr int CDIM   = 128;
constexpr int KCODES = 1024;
constexpr int HWSZ   = 4096;   // 64*64
constexpr int BATCH  = 16;
constexpr int NPOS   = BATCH * HWSZ;            // 65536
constexpr int P      = 64;                      // positions per block
constexpr int TK     = 64;                      // codes per LDS tile
constexpr int NTILES = KCODES / TK;             // 16
constexpr size_t QELEMS   = (size_t)BATCH * CDIM * HWSZ;   // 8388608
constexpr size_t IDX_OFF  = QELEMS;                        // float32 elements
constexpr size_t LOSS_OFF = IDX_OFF + (size_t)NPOS;        // 8454144
constexpr size_t PERP_OFF = LOSS_OFF + 1;
// d_ws float-element offsets
constexpr int WS_C2   = 0;      // [0,1024)   float ||c_k||^2 (numpy-bit-exact)
constexpr int WS_HIST = 1024;   // [1024,2048) uint  usage counts
constexpr int WS_LOSS = 2048;   // [2048]     float sum ||z-q||^2
constexpr float INV_TOTAL = 1.0f / (float)QELEMS;
constexpr float INV_NPOS  = 1.0f / (float)NPOS;
}

// Bit-exact replica of numpy pairwise_sum for n=128 contiguous float32 applied
// to elementwise squares: 8 accumulator chains (stride 8), sequential within a
// chain, combined ((r0+r1)+(r2+r3))+((r4+r5)+(r6+r7)). __f*_rn forbids fma
// contraction (numpy multiplies into a temp, then adds — never fused).
__device__ __forceinline__ float np_sumsq_128(const float* v) {
    float r[8];
    #pragma unroll
    for (int j = 0; j < 8; ++j) r[j] = __fmul_rn(v[j], v[j]);
    #pragma unroll
    for (int i = 8; i < 128; i += 8) {
        #pragma unroll
        for (int j = 0; j < 8; ++j)
            r[j] = __fadd_rn(r[j], __fmul_rn(v[i + j], v[i + j]));
    }
    const float s01 = __fadd_rn(r[0], r[1]);
    const float s23 = __fadd_rn(r[2], r[3]);
    const float s45 = __fadd_rn(r[4], r[5]);
    const float s67 = __fadd_rn(r[6], r[7]);
    return __fadd_rn(__fadd_rn(s01, s23), __fadd_rn(s45, s67));
}

// ---- pass 0: codebook norms (numpy-bit-exact) + zero accumulators ----------
__global__ __launch_bounds__(256) void vq_prep(const float* __restrict__ cb,
                                               float* __restrict__ ws) {
    const int k = blockIdx.x * 256 + threadIdx.x;   // 0..1023
    const float* row = cb + (size_t)k * CDIM;
    float rr[CDIM];
    #pragma unroll
    for (int c = 0; c < CDIM; ++c) rr[c] = row[c];
    ws[WS_C2 + k] = np_sumsq_128(rr);
    ((unsigned int*)ws)[WS_HIST + k] = 0u;
    if (k == 0) ws[WS_LOSS] = 0.0f;
}

// ---- pass 1: register-blocked GEMM-style argmin -----------------------------
// Round 2: same register-tiled structure, but sized for 2 waves/SIMD.
// R2 measured: 1 block/CU (112.6KB LDS) -> 1 wave/SIMD -> VALUBusy 50% (un-
// hidden ds_read latency). Now P=64: LDS ~74KB -> 2 blocks/CU, 8 waves/CU =
// 2 waves/SIMD; second wave fills lgkmcnt stall slots. Thread tile 2 pos x 8
// codes; inner loop chunked by 4 channels with float4 code reads: 12 DS inst
// per 64 FMAs (was 9 per 32). Code reads have 2 distinct addrs/wave = free
// 2-way broadcast. Bit-exactness: per (pos,code) ONE ascending-c fma chain
// (c,c+1,c+2,c+3 explicit order, chunks ascend); z2 numpy pairwise 8-chain;
// d = fl(fl(z2-2zc)+c2); strict-< ascending-k; cross-subset lexicographic
// (d,k) min == np.argmin first-index tie-break.
__global__ __launch_bounds__(256, 2) void vq_main(const float* __restrict__ z,
                                                  const float* __restrict__ cb,
                                                  float* __restrict__ ws,
                                                  float* __restrict__ out) {
    __shared__ __align__(16) float zt[CDIM][P];     // 32 KB  zt[c][p]
    __shared__ __align__(16) float tile[TK][CDIM];  // 32 KB  tile[k][c]
    __shared__ float z2s[P];                        // 256 B
    __shared__ float bdls[8][P];                    // 2 KB  per-cg best_d
    __shared__ int   bkls[8][P];                    // 2 KB  per-cg best_k
    __shared__ int   wkls[P];                       // 256 B winning code
    __shared__ float red[256];                      // 1 KB
    __shared__ unsigned int lhist[KCODES];          // 4 KB   (total ~73.5 KB)

    const int tid   = threadIdx.x;
    const int nbase = blockIdx.x * P;
    const int b     = nbase >> 12;          // 4096 positions per batch image
    const int hw0   = nbase & (HWSZ - 1);   // 64-aligned
    const float* zb = z + (size_t)b * CDIM * HWSZ + hw0;

    for (int i = tid; i < KCODES; i += 256) lhist[i] = 0u;

    // ---- stage z strip: zt[c][p] = z[b][c][hw0+p] (coalesced) --------------
    #pragma unroll
    for (int i = 0; i < (CDIM * P / 4) / 256; ++i) {   // 8 iters
        const int linear = i * 256 + tid;              // 0..2047
        const int c  = linear >> 4;                    // 16 float4 per c-row
        const int p4 = (linear & 15) * 4;
        *(float4*)&zt[c][p4] = *(const float4*)(zb + (size_t)c * HWSZ + p4);
    }
    __syncthreads();

    // ---- z2 per position: numpy pairwise 8-chain, streamed from LDS --------
    if (tid < P) {
        const int p = tid;
        float r[8];
        #pragma unroll
        for (int j = 0; j < 8; ++j) {
            const float x = zt[j][p];
            r[j] = __fmul_rn(x, x);
        }
        #pragma unroll
        for (int i = 8; i < CDIM; i += 8) {
            #pragma unroll
            for (int j = 0; j < 8; ++j) {
                const float x = zt[i + j][p];
                r[j] = __fadd_rn(r[j], __fmul_rn(x, x));
            }
        }
        const float s01 = __fadd_rn(r[0], r[1]);
        const float s23 = __fadd_rn(r[2], r[3]);
        const float s45 = __fadd_rn(r[4], r[5]);
        const float s67 = __fadd_rn(r[6], r[7]);
        z2s[p] = __fadd_rn(__fadd_rn(s01, s23), __fadd_rn(s45, s67));
    }
    __syncthreads();

    const int pg = tid & 31;     // position group: positions p0, p0+1
    const int cg = tid >> 5;     // code group 0..7: codes k0..k0+7 per tile
    const int p0 = pg * 2;
    const int k0 = cg * 8;
    const float* c2g = ws + WS_C2;

    const float z2r0 = z2s[p0 + 0];
    const float z2r1 = z2s[p0 + 1];

    float bestd[2] = {INFINITY, INFINITY};
    int   bestk[2] = {0, 0};

    for (int t = 0; t < NTILES; ++t) {
        __syncthreads();
        {   // stage code tile [k][c]: straight contiguous copy
            const float4* src = (const float4*)(cb + (size_t)t * TK * CDIM);
            float4* dst = (float4*)tile;
            #pragma unroll
            for (int i = 0; i < (TK * CDIM / 4) / 256; ++i)   // 8 iters
                dst[i * 256 + tid] = src[i * 256 + tid];
        }
        __syncthreads();

        float a[2][8];
        #pragma unroll
        for (int j = 0; j < 8; ++j) { a[0][j] = 0.0f; a[1][j] = 0.0f; }

        // 16 independent fma chains, each ascending c (reference order).
        #pragma unroll 2
        for (int c4 = 0; c4 < CDIM / 4; ++c4) {
            const int c = c4 * 4;
            const float2 zv0 = *(const float2*)&zt[c + 0][p0];
            const float2 zv1 = *(const float2*)&zt[c + 1][p0];
            const float2 zv2 = *(const float2*)&zt[c + 2][p0];
            const float2 zv3 = *(const float2*)&zt[c + 3][p0];
            #pragma unroll
            for (int j = 0; j < 8; ++j) {
                const float4 cv = *(const float4*)&tile[k0 + j][c];
                a[0][j] = fmaf(zv0.x, cv.x, a[0][j]);
                a[0][j] = fmaf(zv1.x, cv.y, a[0][j]);
                a[0][j] = fmaf(zv2.x, cv.z, a[0][j]);
                a[0][j] = fmaf(zv3.x, cv.w, a[0][j]);
                a[1][j] = fmaf(zv0.y, cv.x, a[1][j]);
                a[1][j] = fmaf(zv1.y, cv.y, a[1][j]);
                a[1][j] = fmaf(zv2.y, cv.z, a[1][j]);
                a[1][j] = fmaf(zv3.y, cv.w, a[1][j]);
            }
        }

        // d = fl(fl(z2 - 2*zc) + c2); strict < with ascending k (t, then j)
        const int kb = t * TK + k0;
        #pragma unroll
        for (int j = 0; j < 8; ++j) {
            const float c2 = c2g[kb + j];
            const float d0 = __fadd_rn(fmaf(-2.0f, a[0][j], z2r0), c2);
            const float d1 = __fadd_rn(fmaf(-2.0f, a[1][j], z2r1), c2);
            if (d0 < bestd[0]) { bestd[0] = d0; bestk[0] = kb + j; }
            if (d1 < bestd[1]) { bestd[1] = d1; bestk[1] = kb + j; }
        }
    }

    bdls[cg][p0 + 0] = bestd[0];
    bdls[cg][p0 + 1] = bestd[1];
    bkls[cg][p0 + 0] = bestk[0];
    bkls[cg][p0 + 1] = bestk[1];
    __syncthreads();

    // ---- combine 8 disjoint code-subsets per position; lexicographic (d,k)
    if (tid < P) {
        const int p = tid;
        float bd = bdls[0][p];
        int   bk = bkls[0][p];
        #pragma unroll
        for (int g = 1; g < 8; ++g) {
            const float d = bdls[g][p];
            const int   k = bkls[g][p];
            if (d < bd || (d == bd && k < bk)) { bd = d; bk = k; }
        }
        wkls[p] = bk;
        out[IDX_OFF + (size_t)(nbase + p)] = (float)bk;
        atomicAdd(&lhist[bk], 1u);
        red[tid] = bd;     // best_d == fl(||z-q||^2), loss has 2% slack
    } else {
        red[tid] = 0.0f;
    }
    __syncthreads();
    for (int s = 128; s > 0; s >>= 1) {
        if (tid < s) red[tid] += red[tid + s];
        __syncthreads();
    }
    if (tid == 0) atomicAdd(&ws[WS_LOSS], red[0]);

    // ---- quantized output: out[b][c][hw0+p] = cb[wk[p]][c] -----------------
    // stores coalesced (256B per c-row); cb gather L1/L2-hot (block touches
    // <=64 rows = 32KB).
    float* ob = out + (size_t)b * CDIM * HWSZ + hw0;
    #pragma unroll
    for (int i = 0; i < (CDIM * P) / 256; ++i) {   // 32 iters
        const int linear = i * 256 + tid;          // 0..8191
        const int c = linear >> 6;
        const int p = linear & 63;
        ob[(size_t)c * HWSZ + p] = cb[(size_t)wkls[p] * CDIM + c];
    }

    unsigned int* ghist = (unsigned int*)ws + WS_HIST;
    for (int i = tid; i < KCODES; i += 256) {
        const unsigned int v = lhist[i];
        if (v) atomicAdd(&ghist[i], v);
    }
}

// ---- pass 2: scalars --------------------------------------------------------
__global__ __launch_bounds__(1024) void vq_final(const float* __restrict__ ws,
                                                 float* __restrict__ out) {
    __shared__ float red[1024];
    const int t = threadIdx.x;
    const unsigned int* hist = (const unsigned int*)ws + WS_HIST;
    const float p = (float)hist[t] * INV_NPOS;
    red[t] = p * logf(p + 1e-10f);
    __syncthreads();
    for (int s = 512; s > 0; s >>= 1) {
        if (t < s) red[t] += red[t + s];
        __syncthreads();
    }
    if (t == 0) {
        out[LOSS_OFF] = 1.25f * (ws[WS_LOSS] * INV_TOTAL);   // cb + 0.25*commit
        out[PERP_OFF] = expf(-red[0]);
    }
}

extern "C" void kernel_launch(void* const* d_in, const int* in_sizes, int n_in,
                              void* d_out, int out_size, void* d_ws, size_t ws_size,
                              hipStream_t stream) {
    const float* z  = (const float*)d_in[0];
    const float* cb = (const float*)d_in[1];
    float* out = (float*)d_out;
    float* ws  = (float*)d_ws;

    vq_prep <<<KCODES / 256, 256, 0, stream>>>(cb, ws);
    vq_main <<<NPOS / P,     256, 0, stream>>>(z, cb, ws, out);
    vq_final<<<1,           1024, 0, stream>>>(ws, out);
}